// Round 6
// baseline (208.062 us; speedup 1.0000x reference)
//
#include <hip/hip_runtime.h>

// CP-decomposed 3D conv (AirConv3D): B=1, Cin=32, Cout=64, 56^3, K=3, pad=1, rank=53.
// All-f32. R9: no block-splitting reduction readers. R11: branches+redundant
// loads = latency-bound. R12: rank-split+branchless -> 74us. R13: float4+8wave
// +XCD swizzle -> 54us, FETCH 55->28MB, but two-phase structure serializes
// mem/VALU within a block (2 blocks/CU, no cross-block overlap) -> still
// latency-bound at 1.35 TB/s.
// NOTE: ~89us of harness fillBuffer (ws re-poison) is inside the timed window;
// controllable pipeline is ~70us: k3 ~54 + k1d ~13 + k0 ~1.
// R14 (resubmit after infra failure): k3p = software-pipelined double-buffer.
// Groups of 8 ranks (1 rank/wave). Per group: issue next group's 9 float4
// loads EARLY -> project current group from LDS (256 FMA/wave hides latency)
// -> combine+write next -> 1 barrier. LDS 2x8x64xfloat4 = 16 KB. Full unroll
// over 7 groups (compile-time guards).
// Floor: max(mem 72MB/6.3TBs=11.5us, VALU ~10us) -> target 22-28us.
// Pipeline: k0_t -> k1d (pointwise+d-conv via shfl) -> k3p.
// Fallback (small ws): R5 pipeline (known good).

#define NP 175616   // 56*56*56
#define NP4 43904   // NP/4 float4 columns
#define HSTR 3136   // 56*56
#define H4 784      // HSTR/4 float4 per h-plane
#define W4 14       // 56/4 float4 per w-row
#define CIN 32
#define RK 53
#define COUT 64
#define SCR 53      // fallback scratch slice base in d_out

// ---- k0: Ut[r*32+c] = Ucin[c*53+r] ----
__global__ __launch_bounds__(256) void k0_t(const float* __restrict__ Ucin,
                                            float* __restrict__ Ut)
{
    int t = blockIdx.x * 256 + threadIdx.x;
    if (t < RK * CIN) {
        int r = t >> 5, c = t & 31;
        Ut[t] = Ucin[c * RK + r];
    }
}

// ---- k1d: T1d[r,p] = d-conv(sum_c x[c,p]*Ut[r][c]) via wave shfl ----
__global__ __launch_bounds__(256) void k1d(
    const float* __restrict__ x, const float* __restrict__ Ut,
    const float* __restrict__ Ukd, float* __restrict__ T1d)
{
    const int lane = threadIdx.x & 63;          // d index
    const int row  = blockIdx.x * 4 + (threadIdx.x >> 6);   // (h,w) row in [0,3136)
    const int p    = row * 56 + lane;
    const bool act = (lane < 56);

    float xv[CIN];
#pragma unroll
    for (int c = 0; c < CIN; ++c) xv[c] = act ? x[c * NP + p] : 0.f;

#pragma unroll 2
    for (int r = 0; r < RK; ++r) {
        const float* U = Ut + r * CIN;          // uniform -> s_load
        float acc = 0.f;
#pragma unroll
        for (int c = 0; c < CIN; ++c) acc += xv[c] * U[c];
        float lm = __shfl_up(acc, 1, 64);
        float rp = __shfl_down(acc, 1, 64);
        if (lane == 0)  lm = 0.f;
        if (lane == 55) rp = 0.f;
        float res = lm * Ukd[r] + acc * Ukd[RK + r] + rp * Ukd[2 * RK + r];
        if (act) T1d[(size_t)r * NP + p] = res;
    }
}

// ---- k3p: pipelined w+h conv + 53->64 projection + bias ----
// Wave wv stages rank g*8+wv each group; all waves project all 8 ranks of the
// previous group from LDS while next group's loads are in flight.
__global__ __launch_bounds__(512, 4) void k3p(
    const float4* __restrict__ Ta, const float* __restrict__ Ucout,
    const float* __restrict__ bias, const float* __restrict__ Ukh,
    const float* __restrict__ Ukw, float4* __restrict__ Out)
{
    __shared__ float4 tld[2][8][64];             // 16 KB double buffer

    const int lane = threadIdx.x & 63;
    const int wv   = threadIdx.x >> 6;           // 0..7

    // bijective XCD swizzle (m204)
    const int nwg = gridDim.x;                   // 686
    const int qx = nwg >> 3, rx = nwg & 7;
    const int xcd = blockIdx.x & 7, loc = blockIdx.x >> 3;
    const int swz = ((xcd < rx) ? xcd * (qx + 1) : rx * (qx + 1) + (xcd - rx) * qx) + loc;

    const int q4 = swz * 64 + lane;              // float4 column in [0,NP4)
    const int h  = q4 / H4;
    const int rm = q4 - h * H4;
    const int w  = rm / W4;
    const bool hm = (h > 0), hp = (h < 55);
    const bool wm = (w > 0), wp = (w < 55);
    const int om = hm ? -H4 : 0;
    const int op = hp ?  H4 : 0;
    const int oa = wm ? -W4 : 0;
    const int oc = wp ?  W4 : 0;

    const float4* Sq = Ta + q4;

    const int og = __builtin_amdgcn_readfirstlane((threadIdx.x >> 6) << 3); // 0,8,..56

    float4 a[8];
#pragma unroll
    for (int o = 0; o < 8; ++o) {
        float b = bias[og + o];
        a[o].x = b; a[o].y = b; a[o].z = b; a[o].w = b;
    }

#define LOAD9(S) \
    v00 = (S)[om + oa]; v01 = (S)[om]; v02 = (S)[om + oc]; \
    v10 = (S)[oa];      v11 = (S)[0];  v12 = (S)[oc];      \
    v20 = (S)[op + oa]; v21 = (S)[op]; v22 = (S)[op + oc];

#define WHBLEND(t, r) { \
    const float kw0 = wm ? Ukw[r] : 0.f; \
    const float kw1 = Ukw[RK + (r)]; \
    const float kw2 = wp ? Ukw[2 * RK + (r)] : 0.f; \
    const float kh0 = hm ? Ukh[r] : 0.f; \
    const float kh1 = Ukh[RK + (r)]; \
    const float kh2 = hp ? Ukh[2 * RK + (r)] : 0.f; \
    t.x = (v00.x * kw0 + v01.x * kw1 + v02.x * kw2) * kh0 \
        + (v10.x * kw0 + v11.x * kw1 + v12.x * kw2) * kh1 \
        + (v20.x * kw0 + v21.x * kw1 + v22.x * kw2) * kh2; \
    t.y = (v00.y * kw0 + v01.y * kw1 + v02.y * kw2) * kh0 \
        + (v10.y * kw0 + v11.y * kw1 + v12.y * kw2) * kh1 \
        + (v20.y * kw0 + v21.y * kw1 + v22.y * kw2) * kh2; \
    t.z = (v00.z * kw0 + v01.z * kw1 + v02.z * kw2) * kh0 \
        + (v10.z * kw0 + v11.z * kw1 + v12.z * kw2) * kh1 \
        + (v20.z * kw0 + v21.z * kw1 + v22.z * kw2) * kh2; \
    t.w = (v00.w * kw0 + v01.w * kw1 + v02.w * kw2) * kh0 \
        + (v10.w * kw0 + v11.w * kw1 + v12.w * kw2) * kh1 \
        + (v20.w * kw0 + v21.w * kw1 + v22.w * kw2) * kh2; }

    float4 v00, v01, v02, v10, v11, v12, v20, v21, v22;

    // prologue: stage group 0 (rank = wv)
    {
        const float4* S = Sq + (size_t)wv * NP4;
        LOAD9(S);
        float4 t;
        WHBLEND(t, wv);
        tld[0][wv][lane] = t;
    }
    __syncthreads();

#pragma unroll
    for (int g = 0; g < 7; ++g) {
        const int rn = (g + 1) * 8 + wv;             // rank to stage next
        const bool hn = (g < 6) && (rn < RK);        // wave-uniform guard
        if (hn) {
            const float4* S = Sq + (size_t)rn * NP4;
            LOAD9(S);                                // issue early; used after proj
        }
        // project group g from LDS
        const int n = (g == 6) ? 5 : 8;
#pragma unroll
        for (int rr = 0; rr < 8; ++rr) {
            if (rr < n) {
                float4 t = tld[g & 1][rr][lane];
                const float* Ur = Ucout + (g * 8 + rr) * COUT + og;  // s_load
#pragma unroll
                for (int o = 0; o < 8; ++o) {
                    float u = Ur[o];
                    a[o].x += t.x * u; a[o].y += t.y * u;
                    a[o].z += t.z * u; a[o].w += t.w * u;
                }
            }
        }
        if (hn) {
            float4 t;
            WHBLEND(t, rn);                          // vmcnt wait lands here
            tld[(g + 1) & 1][wv][lane] = t;
        }
        if (g < 6) __syncthreads();
    }

#pragma unroll
    for (int o = 0; o < 8; ++o)
        Out[(size_t)(og + o) * NP4 + q4] = a[o];
#undef LOAD9
#undef WHBLEND
}

// ===================== fallback path (R5, known good) =====================

__global__ __launch_bounds__(256) void k1_chunk(
    const float* __restrict__ x, const float* __restrict__ Ucin,
    float* T, int r0, int nr)
{
    __shared__ float sU[11 * CIN];
    const int tid = threadIdx.x;
    for (int t = tid; t < nr * CIN; t += 256) {
        int lr = t >> 5, c = t & 31;
        sU[t] = Ucin[c * RK + (r0 + lr)];
    }
    __syncthreads();
    const int p = blockIdx.x * 256 + tid;
    float xv[CIN];
#pragma unroll
    for (int c = 0; c < CIN; ++c) xv[c] = x[c * NP + p];
#pragma unroll 1
    for (int lr = 0; lr < nr; ++lr) {
        float acc = 0.f;
#pragma unroll
        for (int c = 0; c < CIN; ++c) acc += xv[c] * sU[lr * CIN + c];
        T[(size_t)(SCR + lr) * NP + p] = acc;
    }
}

__global__ __launch_bounds__(256) void k2_chunk(
    const float* __restrict__ Ukh, const float* __restrict__ Ukw,
    const float* __restrict__ Ukd, float* T, int r0)
{
    __shared__ float sIn[5800];
    __shared__ float sA[5600];
    const int lr = blockIdx.z;
    const int r  = r0 + lr;
    const int h0 = blockIdx.x * 8, w0 = blockIdx.y * 8;
    const int tid = threadIdx.x;
    const float kh0 = Ukh[r], kh1 = Ukh[RK + r], kh2 = Ukh[2 * RK + r];
    const float kw0 = Ukw[r], kw1 = Ukw[RK + r], kw2 = Ukw[2 * RK + r];
    const float kd0 = Ukd[r], kd1 = Ukd[RK + r], kd2 = Ukd[2 * RK + r];
    const float* T1r = T + (size_t)(SCR + lr) * NP;

    for (int idx = tid; idx < 5800; idx += 256) {
        int d = idx % 58; int t2 = idx / 58; int ww = t2 % 10; int hh = t2 / 10;
        int gh = h0 + hh - 1, gw = w0 + ww - 1, gd = d - 1;
        float v = 0.f;
        if ((unsigned)gh < 56u && (unsigned)gw < 56u && (unsigned)gd < 56u)
            v = T1r[gh * HSTR + gw * 56 + gd];
        sIn[idx] = v;
    }
    __syncthreads();
    for (int idx = tid; idx < 5600; idx += 256) {
        int d = idx % 56; int t2 = idx / 56; int ww = t2 % 10; int hh = t2 / 10;
        const float* b = &sIn[(hh * 10 + ww) * 58 + d];
        sA[idx] = b[0] * kd0 + b[1] * kd1 + b[2] * kd2;
    }
    __syncthreads();
    const float k00 = kh0 * kw0, k01 = kh0 * kw1, k02 = kh0 * kw2;
    const float k10 = kh1 * kw0, k11 = kh1 * kw1, k12 = kh1 * kw2;
    const float k20 = kh2 * kw0, k21 = kh2 * kw1, k22 = kh2 * kw2;
    for (int idx = tid; idx < 3584; idx += 256) {
        int d = idx % 56; int t2 = idx / 56; int ww = t2 % 8; int hh = t2 / 8;
        const float* a = &sA[(hh * 10 + ww) * 56 + d];
        float acc = a[0]    * k00 + a[56]   * k01 + a[112]  * k02
                  + a[560]  * k10 + a[616]  * k11 + a[672]  * k12
                  + a[1120] * k20 + a[1176] * k21 + a[1232] * k22;
        T[(size_t)r * NP + (h0 + hh) * HSTR + (w0 + ww) * 56 + d] = acc;
    }
}

__global__ __launch_bounds__(256) void k3_out(
    float* T, const float* __restrict__ Ucout, const float* __restrict__ bias)
{
    __shared__ float sUo[RK * COUT];
    __shared__ float sB[COUT];
    const int tid = threadIdx.x;
    for (int t = tid; t < RK * COUT; t += 256) sUo[t] = Ucout[t];
    if (tid < COUT) sB[tid] = bias[tid];
    __syncthreads();
    const int p = blockIdx.x * 256 + tid;
    float acc[COUT];
#pragma unroll
    for (int o = 0; o < COUT; ++o) acc[o] = sB[o];
#pragma unroll 1
    for (int r = 0; r < RK; ++r) {
        float t = T[(size_t)r * NP + p];
        const float* Ur = &sUo[r * COUT];
#pragma unroll
        for (int o = 0; o < COUT; ++o) acc[o] += t * Ur[o];
    }
#pragma unroll
    for (int o = 0; o < COUT; ++o) T[(size_t)o * NP + p] = acc[o];
}

// ===================== launch =====================

extern "C" void kernel_launch(void* const* d_in, const int* in_sizes, int n_in,
                              void* d_out, int out_size, void* d_ws, size_t ws_size,
                              hipStream_t stream)
{
    const float* x     = (const float*)d_in[0];
    const float* Ukh   = (const float*)d_in[1];
    const float* Ukw   = (const float*)d_in[2];
    const float* Ukd   = (const float*)d_in[3];
    const float* Ucin  = (const float*)d_in[4];
    const float* Ucout = (const float*)d_in[5];
    const float* bias  = (const float*)d_in[6];

    const size_t t1_bytes = (size_t)RK * NP * sizeof(float);   // 37.2 MB

    if (ws_size >= t1_bytes + 8192) {
        float* T1 = (float*)d_ws;
        float* Ut = (float*)((char*)d_ws + t1_bytes);          // 6.8 KB
        k0_t<<<7, 256, 0, stream>>>(Ucin, Ut);
        k1d<<<HSTR / 4, 256, 0, stream>>>(x, Ut, Ukd, T1);     // 784 blocks
        k3p<<<NP4 / 64, 512, 0, stream>>>((const float4*)T1, Ucout, bias, Ukh,
                                          Ukw, (float4*)d_out);   // 686 blocks
    } else {
        float* T = (float*)d_out;
        for (int r0 = 0; r0 < RK; r0 += 11) {
            int nr = (RK - r0 < 11) ? (RK - r0) : 11;
            k1_chunk<<<NP / 256, 256, 0, stream>>>(x, Ucin, T, r0, nr);
            k2_chunk<<<dim3(7, 7, nr), 256, 0, stream>>>(Ukh, Ukw, Ukd, T, r0);
        }
        k3_out<<<NP / 256, 256, 0, stream>>>(T, Ucout, bias);
    }
}

// Round 7
// 186.578 us; speedup vs baseline: 1.1152x; 1.1152x over previous
//
#include <hip/hip_runtime.h>

// CP-decomposed 3D conv (AirConv3D): B=1, Cin=32, Cout=64, 56^3, K=3, pad=1, rank=53.
// All-f32. R9: no block-splitting reduction readers. R11: branches+redundant
// loads = latency-bound. R12: rank-split+branchless -> 74us. R13: float4+8wave
// +XCD swizzle -> 54us @ FETCH 28MB, two-phase serialization. R14: pipelined
// double-buffer PASSED but __launch_bounds__(512,4) clamped VGPR to 64 ->
// ~100 live regs spilled to scratch: WRITE 242MB / FETCH 129MB, 117us.
// The overlap itself worked (3.4 TB/s) — all spent on spill traffic.
// R15: identical k3p with __launch_bounds__(512, 2) -> VGPR budget >=128,
// no spill. Expect VGPR ~96-110, WRITE ~44MB, FETCH ~30-40MB, k3 ~20-30us.
// NOTE: ~89us of harness fillBuffer (ws re-poison) is inside the timed window;
// controllable pipeline is k3 + k1d (~13us, near traffic roofline) + k0 (~1us).
// Pipeline: k0_t -> k1d (pointwise+d-conv via shfl) -> k3p.
// Fallback (small ws): R5 pipeline (known good).

#define NP 175616   // 56*56*56
#define NP4 43904   // NP/4 float4 columns
#define HSTR 3136   // 56*56
#define H4 784      // HSTR/4 float4 per h-plane
#define W4 14       // 56/4 float4 per w-row
#define CIN 32
#define RK 53
#define COUT 64
#define SCR 53      // fallback scratch slice base in d_out

// ---- k0: Ut[r*32+c] = Ucin[c*53+r] ----
__global__ __launch_bounds__(256) void k0_t(const float* __restrict__ Ucin,
                                            float* __restrict__ Ut)
{
    int t = blockIdx.x * 256 + threadIdx.x;
    if (t < RK * CIN) {
        int r = t >> 5, c = t & 31;
        Ut[t] = Ucin[c * RK + r];
    }
}

// ---- k1d: T1d[r,p] = d-conv(sum_c x[c,p]*Ut[r][c]) via wave shfl ----
__global__ __launch_bounds__(256) void k1d(
    const float* __restrict__ x, const float* __restrict__ Ut,
    const float* __restrict__ Ukd, float* __restrict__ T1d)
{
    const int lane = threadIdx.x & 63;          // d index
    const int row  = blockIdx.x * 4 + (threadIdx.x >> 6);   // (h,w) row in [0,3136)
    const int p    = row * 56 + lane;
    const bool act = (lane < 56);

    float xv[CIN];
#pragma unroll
    for (int c = 0; c < CIN; ++c) xv[c] = act ? x[c * NP + p] : 0.f;

#pragma unroll 2
    for (int r = 0; r < RK; ++r) {
        const float* U = Ut + r * CIN;          // uniform -> s_load
        float acc = 0.f;
#pragma unroll
        for (int c = 0; c < CIN; ++c) acc += xv[c] * U[c];
        float lm = __shfl_up(acc, 1, 64);
        float rp = __shfl_down(acc, 1, 64);
        if (lane == 0)  lm = 0.f;
        if (lane == 55) rp = 0.f;
        float res = lm * Ukd[r] + acc * Ukd[RK + r] + rp * Ukd[2 * RK + r];
        if (act) T1d[(size_t)r * NP + p] = res;
    }
}

// ---- k3p: pipelined w+h conv + 53->64 projection + bias ----
// Wave wv stages rank g*8+wv each group; all waves project all 8 ranks of the
// previous group from LDS while next group's loads are in flight.
// __launch_bounds__(512,2): VGPR budget >=128 so the ~100 live regs
// (36 staging + 32 acc + addressing) do NOT spill (R14 lesson).
__global__ __launch_bounds__(512, 2) void k3p(
    const float4* __restrict__ Ta, const float* __restrict__ Ucout,
    const float* __restrict__ bias, const float* __restrict__ Ukh,
    const float* __restrict__ Ukw, float4* __restrict__ Out)
{
    __shared__ float4 tld[2][8][64];             // 16 KB double buffer

    const int lane = threadIdx.x & 63;
    const int wv   = threadIdx.x >> 6;           // 0..7

    // bijective XCD swizzle (m204)
    const int nwg = gridDim.x;                   // 686
    const int qx = nwg >> 3, rx = nwg & 7;
    const int xcd = blockIdx.x & 7, loc = blockIdx.x >> 3;
    const int swz = ((xcd < rx) ? xcd * (qx + 1) : rx * (qx + 1) + (xcd - rx) * qx) + loc;

    const int q4 = swz * 64 + lane;              // float4 column in [0,NP4)
    const int h  = q4 / H4;
    const int rm = q4 - h * H4;
    const int w  = rm / W4;
    const bool hm = (h > 0), hp = (h < 55);
    const bool wm = (w > 0), wp = (w < 55);
    const int om = hm ? -H4 : 0;
    const int op = hp ?  H4 : 0;
    const int oa = wm ? -W4 : 0;
    const int oc = wp ?  W4 : 0;

    const float4* Sq = Ta + q4;

    const int og = __builtin_amdgcn_readfirstlane((threadIdx.x >> 6) << 3); // 0,8,..56

    float4 a[8];
#pragma unroll
    for (int o = 0; o < 8; ++o) {
        float b = bias[og + o];
        a[o].x = b; a[o].y = b; a[o].z = b; a[o].w = b;
    }

#define LOAD9(S) \
    v00 = (S)[om + oa]; v01 = (S)[om]; v02 = (S)[om + oc]; \
    v10 = (S)[oa];      v11 = (S)[0];  v12 = (S)[oc];      \
    v20 = (S)[op + oa]; v21 = (S)[op]; v22 = (S)[op + oc];

#define WHBLEND(t, r) { \
    const float kw0 = wm ? Ukw[r] : 0.f; \
    const float kw1 = Ukw[RK + (r)]; \
    const float kw2 = wp ? Ukw[2 * RK + (r)] : 0.f; \
    const float kh0 = hm ? Ukh[r] : 0.f; \
    const float kh1 = Ukh[RK + (r)]; \
    const float kh2 = hp ? Ukh[2 * RK + (r)] : 0.f; \
    t.x = (v00.x * kw0 + v01.x * kw1 + v02.x * kw2) * kh0 \
        + (v10.x * kw0 + v11.x * kw1 + v12.x * kw2) * kh1 \
        + (v20.x * kw0 + v21.x * kw1 + v22.x * kw2) * kh2; \
    t.y = (v00.y * kw0 + v01.y * kw1 + v02.y * kw2) * kh0 \
        + (v10.y * kw0 + v11.y * kw1 + v12.y * kw2) * kh1 \
        + (v20.y * kw0 + v21.y * kw1 + v22.y * kw2) * kh2; \
    t.z = (v00.z * kw0 + v01.z * kw1 + v02.z * kw2) * kh0 \
        + (v10.z * kw0 + v11.z * kw1 + v12.z * kw2) * kh1 \
        + (v20.z * kw0 + v21.z * kw1 + v22.z * kw2) * kh2; \
    t.w = (v00.w * kw0 + v01.w * kw1 + v02.w * kw2) * kh0 \
        + (v10.w * kw0 + v11.w * kw1 + v12.w * kw2) * kh1 \
        + (v20.w * kw0 + v21.w * kw1 + v22.w * kw2) * kh2; }

    float4 v00, v01, v02, v10, v11, v12, v20, v21, v22;

    // prologue: stage group 0 (rank = wv)
    {
        const float4* S = Sq + (size_t)wv * NP4;
        LOAD9(S);
        float4 t;
        WHBLEND(t, wv);
        tld[0][wv][lane] = t;
    }
    __syncthreads();

#pragma unroll
    for (int g = 0; g < 7; ++g) {
        const int rn = (g + 1) * 8 + wv;             // rank to stage next
        const bool hn = (g < 6) && (rn < RK);        // wave-uniform guard
        if (hn) {
            const float4* S = Sq + (size_t)rn * NP4;
            LOAD9(S);                                // issue early; used after proj
        }
        // project group g from LDS
        const int n = (g == 6) ? 5 : 8;
#pragma unroll
        for (int rr = 0; rr < 8; ++rr) {
            if (rr < n) {
                float4 t = tld[g & 1][rr][lane];
                const float* Ur = Ucout + (g * 8 + rr) * COUT + og;  // s_load
#pragma unroll
                for (int o = 0; o < 8; ++o) {
                    float u = Ur[o];
                    a[o].x += t.x * u; a[o].y += t.y * u;
                    a[o].z += t.z * u; a[o].w += t.w * u;
                }
            }
        }
        if (hn) {
            float4 t;
            WHBLEND(t, rn);                          // vmcnt wait lands here
            tld[(g + 1) & 1][wv][lane] = t;
        }
        if (g < 6) __syncthreads();
    }

#pragma unroll
    for (int o = 0; o < 8; ++o)
        Out[(size_t)(og + o) * NP4 + q4] = a[o];
#undef LOAD9
#undef WHBLEND
}

// ===================== fallback path (R5, known good) =====================

__global__ __launch_bounds__(256) void k1_chunk(
    const float* __restrict__ x, const float* __restrict__ Ucin,
    float* T, int r0, int nr)
{
    __shared__ float sU[11 * CIN];
    const int tid = threadIdx.x;
    for (int t = tid; t < nr * CIN; t += 256) {
        int lr = t >> 5, c = t & 31;
        sU[t] = Ucin[c * RK + (r0 + lr)];
    }
    __syncthreads();
    const int p = blockIdx.x * 256 + tid;
    float xv[CIN];
#pragma unroll
    for (int c = 0; c < CIN; ++c) xv[c] = x[c * NP + p];
#pragma unroll 1
    for (int lr = 0; lr < nr; ++lr) {
        float acc = 0.f;
#pragma unroll
        for (int c = 0; c < CIN; ++c) acc += xv[c] * sU[lr * CIN + c];
        T[(size_t)(SCR + lr) * NP + p] = acc;
    }
}

__global__ __launch_bounds__(256) void k2_chunk(
    const float* __restrict__ Ukh, const float* __restrict__ Ukw,
    const float* __restrict__ Ukd, float* T, int r0)
{
    __shared__ float sIn[5800];
    __shared__ float sA[5600];
    const int lr = blockIdx.z;
    const int r  = r0 + lr;
    const int h0 = blockIdx.x * 8, w0 = blockIdx.y * 8;
    const int tid = threadIdx.x;
    const float kh0 = Ukh[r], kh1 = Ukh[RK + r], kh2 = Ukh[2 * RK + r];
    const float kw0 = Ukw[r], kw1 = Ukw[RK + r], kw2 = Ukw[2 * RK + r];
    const float kd0 = Ukd[r], kd1 = Ukd[RK + r], kd2 = Ukd[2 * RK + r];
    const float* T1r = T + (size_t)(SCR + lr) * NP;

    for (int idx = tid; idx < 5800; idx += 256) {
        int d = idx % 58; int t2 = idx / 58; int ww = t2 % 10; int hh = t2 / 10;
        int gh = h0 + hh - 1, gw = w0 + ww - 1, gd = d - 1;
        float v = 0.f;
        if ((unsigned)gh < 56u && (unsigned)gw < 56u && (unsigned)gd < 56u)
            v = T1r[gh * HSTR + gw * 56 + gd];
        sIn[idx] = v;
    }
    __syncthreads();
    for (int idx = tid; idx < 5600; idx += 256) {
        int d = idx % 56; int t2 = idx / 56; int ww = t2 % 10; int hh = t2 / 10;
        const float* b = &sIn[(hh * 10 + ww) * 58 + d];
        sA[idx] = b[0] * kd0 + b[1] * kd1 + b[2] * kd2;
    }
    __syncthreads();
    const float k00 = kh0 * kw0, k01 = kh0 * kw1, k02 = kh0 * kw2;
    const float k10 = kh1 * kw0, k11 = kh1 * kw1, k12 = kh1 * kw2;
    const float k20 = kh2 * kw0, k21 = kh2 * kw1, k22 = kh2 * kw2;
    for (int idx = tid; idx < 3584; idx += 256) {
        int d = idx % 56; int t2 = idx / 56; int ww = t2 % 8; int hh = t2 / 8;
        const float* a = &sA[(hh * 10 + ww) * 56 + d];
        float acc = a[0]    * k00 + a[56]   * k01 + a[112]  * k02
                  + a[560]  * k10 + a[616]  * k11 + a[672]  * k12
                  + a[1120] * k20 + a[1176] * k21 + a[1232] * k22;
        T[(size_t)r * NP + (h0 + hh) * HSTR + (w0 + ww) * 56 + d] = acc;
    }
}

__global__ __launch_bounds__(256) void k3_out(
    float* T, const float* __restrict__ Ucout, const float* __restrict__ bias)
{
    __shared__ float sUo[RK * COUT];
    __shared__ float sB[COUT];
    const int tid = threadIdx.x;
    for (int t = tid; t < RK * COUT; t += 256) sUo[t] = Ucout[t];
    if (tid < COUT) sB[tid] = bias[tid];
    __syncthreads();
    const int p = blockIdx.x * 256 + tid;
    float acc[COUT];
#pragma unroll
    for (int o = 0; o < COUT; ++o) acc[o] = sB[o];
#pragma unroll 1
    for (int r = 0; r < RK; ++r) {
        float t = T[(size_t)r * NP + p];
        const float* Ur = &sUo[r * COUT];
#pragma unroll
        for (int o = 0; o < COUT; ++o) acc[o] += t * Ur[o];
    }
#pragma unroll
    for (int o = 0; o < COUT; ++o) T[(size_t)o * NP + p] = acc[o];
}

// ===================== launch =====================

extern "C" void kernel_launch(void* const* d_in, const int* in_sizes, int n_in,
                              void* d_out, int out_size, void* d_ws, size_t ws_size,
                              hipStream_t stream)
{
    const float* x     = (const float*)d_in[0];
    const float* Ukh   = (const float*)d_in[1];
    const float* Ukw   = (const float*)d_in[2];
    const float* Ukd   = (const float*)d_in[3];
    const float* Ucin  = (const float*)d_in[4];
    const float* Ucout = (const float*)d_in[5];
    const float* bias  = (const float*)d_in[6];

    const size_t t1_bytes = (size_t)RK * NP * sizeof(float);   // 37.2 MB

    if (ws_size >= t1_bytes + 8192) {
        float* T1 = (float*)d_ws;
        float* Ut = (float*)((char*)d_ws + t1_bytes);          // 6.8 KB
        k0_t<<<7, 256, 0, stream>>>(Ucin, Ut);
        k1d<<<HSTR / 4, 256, 0, stream>>>(x, Ut, Ukd, T1);     // 784 blocks
        k3p<<<NP4 / 64, 512, 0, stream>>>((const float4*)T1, Ucout, bias, Ukh,
                                          Ukw, (float4*)d_out);   // 686 blocks
    } else {
        float* T = (float*)d_out;
        for (int r0 = 0; r0 < RK; r0 += 11) {
            int nr = (RK - r0 < 11) ? (RK - r0) : 11;
            k1_chunk<<<NP / 256, 256, 0, stream>>>(x, Ucin, T, r0, nr);
            k2_chunk<<<dim3(7, 7, nr), 256, 0, stream>>>(Ukh, Ukw, Ukd, T, r0);
        }
        k3_out<<<NP / 256, 256, 0, stream>>>(T, Ucout, bias);
    }
}

// Round 8
// 144.867 us; speedup vs baseline: 1.4362x; 1.2879x over previous
//
#include <hip/hip_runtime.h>

// CP-decomposed 3D conv (AirConv3D): B=1, Cin=32, Cout=64, 56^3, K=3, pad=1, rank=53.
// All-f32. History: R11 branches=latency-bound; R12 rank-split 74us; R13 float4
// 8-wave two-phase 54us (VALU-busy 11us ~= min, HBM-busy 12us ~= min -> STALL-
// bound, both pipes 75% idle; LDS 54KB -> 2 blocks/CU); R14 pipelined +
// (512,4) clamp VGPR 64 vs ~100 live -> spill catastrophe (WRITE 242MB);
// R15 (512,2) VGPR 128 no-spill but 16 waves/CU -> 84us. LESSON: on this
// toolchain __launch_bounds__ 2nd arg acts as min BLOCKS/CU: (512,4)->cap 64,
// (512,2)->cap 128. The lever is TLP (waves/CU), not in-block pipelining.
// R16: k3c = R13's two-phase + rank-chunking (27+26) + float2 lanes:
//   LDS 13.8KB, acc 16 VGPR, est ~54 live <= 64 cap via (512,4) ->
//   4 blocks/CU = 32 waves/CU (2x R13). Grid 1372 (full first round).
//   Go/no-go: VGPR<=64 and WRITE==44MB (no spill).
// NOTE: ~89us of harness fillBuffer (ws re-poison) is inside the timed window;
// controllable pipeline is k3 + k1d (~13us, near traffic roofline) + k0 (~1us).
// Pipeline: k0_t -> k1d (pointwise+d-conv via shfl) -> k3c.
// Fallback (small ws): R5 pipeline (known good).

#define NP 175616   // 56*56*56
#define NP2 87808   // NP/2 float2 columns
#define HSTR 3136   // 56*56
#define H2 1568     // HSTR/2 float2 per h-plane
#define W2 28       // 56/2 float2 per w-row
#define CIN 32
#define RK 53
#define RC0 27      // chunk 0 ranks [0,27)
#define COUT 64
#define SCR 53      // fallback scratch slice base in d_out

// ---- k0: Ut[r*32+c] = Ucin[c*53+r] ----
__global__ __launch_bounds__(256) void k0_t(const float* __restrict__ Ucin,
                                            float* __restrict__ Ut)
{
    int t = blockIdx.x * 256 + threadIdx.x;
    if (t < RK * CIN) {
        int r = t >> 5, c = t & 31;
        Ut[t] = Ucin[c * RK + r];
    }
}

// ---- k1d: T1d[r,p] = d-conv(sum_c x[c,p]*Ut[r][c]) via wave shfl ----
__global__ __launch_bounds__(256) void k1d(
    const float* __restrict__ x, const float* __restrict__ Ut,
    const float* __restrict__ Ukd, float* __restrict__ T1d)
{
    const int lane = threadIdx.x & 63;          // d index
    const int row  = blockIdx.x * 4 + (threadIdx.x >> 6);   // (h,w) row in [0,3136)
    const int p    = row * 56 + lane;
    const bool act = (lane < 56);

    float xv[CIN];
#pragma unroll
    for (int c = 0; c < CIN; ++c) xv[c] = act ? x[c * NP + p] : 0.f;

#pragma unroll 2
    for (int r = 0; r < RK; ++r) {
        const float* U = Ut + r * CIN;          // uniform -> s_load
        float acc = 0.f;
#pragma unroll
        for (int c = 0; c < CIN; ++c) acc += xv[c] * U[c];
        float lm = __shfl_up(acc, 1, 64);
        float rp = __shfl_down(acc, 1, 64);
        if (lane == 0)  lm = 0.f;
        if (lane == 55) rp = 0.f;
        float res = lm * Ukd[r] + acc * Ukd[RK + r] + rp * Ukd[2 * RK + r];
        if (act) T1d[(size_t)r * NP + p] = res;
    }
}

// ---- k3c: two-phase chunked w+h conv + 53->64 projection + bias ----
// Chunk = 27 (then 26) ranks. Phase1: wave wv stages ranks r=c0+wv, +=8 into
// LDS (9 float2 loads, branchless offset-select + 0/1-mask weights).
// Phase2: all waves project the chunk's ranks from LDS (8 ch/wave, SGPR U).
// 32 waves/CU target: VGPR<=64 via (512,4) [= min 4 blocks/CU on this
// toolchain], LDS 13.8KB.
__global__ __launch_bounds__(512, 4) void k3c(
    const float2* __restrict__ Ta, const float* __restrict__ Ucout,
    const float* __restrict__ bias, const float* __restrict__ Ukh,
    const float* __restrict__ Ukw, float2* __restrict__ Out)
{
    __shared__ float2 tld[RC0][64];              // 13824 B

    const int lane = threadIdx.x & 63;
    const int wv   = threadIdx.x >> 6;           // 0..7

    // bijective XCD swizzle (m204); nwg = 1372
    const int nwg = gridDim.x;
    const int qx = nwg >> 3, rx = nwg & 7;
    const int xcd = blockIdx.x & 7, loc = blockIdx.x >> 3;
    const int swz = ((xcd < rx) ? xcd * (qx + 1) : rx * (qx + 1) + (xcd - rx) * qx) + loc;

    const int q  = swz * 64 + lane;              // float2 column in [0,NP2)
    const int h  = q / H2;
    const int rm = q - h * H2;
    const int w  = rm / W2;
    // boundary -> address select + 0/1 weight masks (persistent, branchless)
    const int om = (h > 0)  ? -H2 : 0;
    const int op = (h < 55) ?  H2 : 0;
    const int oa = (w > 0)  ? -W2 : 0;
    const int oc = (w < 55) ?  W2 : 0;
    const float mh0 = (h > 0)  ? 1.f : 0.f;
    const float mh2 = (h < 55) ? 1.f : 0.f;
    const float mw0 = (w > 0)  ? 1.f : 0.f;
    const float mw2 = (w < 55) ? 1.f : 0.f;

    const float2* Sq = Ta + q;
    const int og = __builtin_amdgcn_readfirstlane(wv << 3);  // 0,8,...,56

    float2 a[8];

    // ================= chunk 0: ranks [0,27) =================
    // ---- phase 1 (acc not yet live -> low pressure) ----
#pragma unroll 1
    for (int r = wv; r < RC0; r += 8) {
        const float2* S = Sq + (size_t)r * NP2;
        const float kw0 = mw0 * Ukw[r];
        const float kw1 = Ukw[RK + r];
        const float kw2 = mw2 * Ukw[2 * RK + r];
        const float kh0 = mh0 * Ukh[r];
        const float kh1 = Ukh[RK + r];
        const float kh2 = mh2 * Ukh[2 * RK + r];
        float2 v00 = S[om + oa], v01 = S[om], v02 = S[om + oc];
        float2 v10 = S[oa],      v11 = S[0],  v12 = S[oc];
        float2 v20 = S[op + oa], v21 = S[op], v22 = S[op + oc];
        float2 t;
        t.x = (v00.x * kw0 + v01.x * kw1 + v02.x * kw2) * kh0
            + (v10.x * kw0 + v11.x * kw1 + v12.x * kw2) * kh1
            + (v20.x * kw0 + v21.x * kw1 + v22.x * kw2) * kh2;
        t.y = (v00.y * kw0 + v01.y * kw1 + v02.y * kw2) * kh0
            + (v10.y * kw0 + v11.y * kw1 + v12.y * kw2) * kh1
            + (v20.y * kw0 + v21.y * kw1 + v22.y * kw2) * kh2;
        tld[r][lane] = t;
    }
    __syncthreads();

    // acc init (bias via uniform s_load)
#pragma unroll
    for (int o = 0; o < 8; ++o) {
        float b = bias[og + o];
        a[o].x = b; a[o].y = b;
    }
    // ---- phase 2 ----
#pragma unroll 4
    for (int r = 0; r < RC0; ++r) {
        float2 t = tld[r][lane];
        const float* Ur = Ucout + r * COUT + og;         // uniform -> s_load
#pragma unroll
        for (int o = 0; o < 8; ++o) {
            float u = Ur[o];
            a[o].x += t.x * u; a[o].y += t.y * u;
        }
    }
    __syncthreads();                                     // protect LDS overwrite

    // ================= chunk 1: ranks [27,53) =================
#pragma unroll 1
    for (int r = RC0 + wv; r < RK; r += 8) {
        const float2* S = Sq + (size_t)r * NP2;
        const float kw0 = mw0 * Ukw[r];
        const float kw1 = Ukw[RK + r];
        const float kw2 = mw2 * Ukw[2 * RK + r];
        const float kh0 = mh0 * Ukh[r];
        const float kh1 = Ukh[RK + r];
        const float kh2 = mh2 * Ukh[2 * RK + r];
        float2 v00 = S[om + oa], v01 = S[om], v02 = S[om + oc];
        float2 v10 = S[oa],      v11 = S[0],  v12 = S[oc];
        float2 v20 = S[op + oa], v21 = S[op], v22 = S[op + oc];
        float2 t;
        t.x = (v00.x * kw0 + v01.x * kw1 + v02.x * kw2) * kh0
            + (v10.x * kw0 + v11.x * kw1 + v12.x * kw2) * kh1
            + (v20.x * kw0 + v21.x * kw1 + v22.x * kw2) * kh2;
        t.y = (v00.y * kw0 + v01.y * kw1 + v02.y * kw2) * kh0
            + (v10.y * kw0 + v11.y * kw1 + v12.y * kw2) * kh1
            + (v20.y * kw0 + v21.y * kw1 + v22.y * kw2) * kh2;
        tld[r - RC0][lane] = t;
    }
    __syncthreads();

#pragma unroll 4
    for (int r = RC0; r < RK; ++r) {
        float2 t = tld[r - RC0][lane];
        const float* Ur = Ucout + r * COUT + og;
#pragma unroll
        for (int o = 0; o < 8; ++o) {
            float u = Ur[o];
            a[o].x += t.x * u; a[o].y += t.y * u;
        }
    }

#pragma unroll
    for (int o = 0; o < 8; ++o)
        Out[(size_t)(og + o) * NP2 + q] = a[o];
}

// ===================== fallback path (R5, known good) =====================

__global__ __launch_bounds__(256) void k1_chunk(
    const float* __restrict__ x, const float* __restrict__ Ucin,
    float* T, int r0, int nr)
{
    __shared__ float sU[11 * CIN];
    const int tid = threadIdx.x;
    for (int t = tid; t < nr * CIN; t += 256) {
        int lr = t >> 5, c = t & 31;
        sU[t] = Ucin[c * RK + (r0 + lr)];
    }
    __syncthreads();
    const int p = blockIdx.x * 256 + tid;
    float xv[CIN];
#pragma unroll
    for (int c = 0; c < CIN; ++c) xv[c] = x[c * NP + p];
#pragma unroll 1
    for (int lr = 0; lr < nr; ++lr) {
        float acc = 0.f;
#pragma unroll
        for (int c = 0; c < CIN; ++c) acc += xv[c] * sU[lr * CIN + c];
        T[(size_t)(SCR + lr) * NP + p] = acc;
    }
}

__global__ __launch_bounds__(256) void k2_chunk(
    const float* __restrict__ Ukh, const float* __restrict__ Ukw,
    const float* __restrict__ Ukd, float* T, int r0)
{
    __shared__ float sIn[5800];
    __shared__ float sA[5600];
    const int lr = blockIdx.z;
    const int r  = r0 + lr;
    const int h0 = blockIdx.x * 8, w0 = blockIdx.y * 8;
    const int tid = threadIdx.x;
    const float kh0 = Ukh[r], kh1 = Ukh[RK + r], kh2 = Ukh[2 * RK + r];
    const float kw0 = Ukw[r], kw1 = Ukw[RK + r], kw2 = Ukw[2 * RK + r];
    const float kd0 = Ukd[r], kd1 = Ukd[RK + r], kd2 = Ukd[2 * RK + r];
    const float* T1r = T + (size_t)(SCR + lr) * NP;

    for (int idx = tid; idx < 5800; idx += 256) {
        int d = idx % 58; int t2 = idx / 58; int ww = t2 % 10; int hh = t2 / 10;
        int gh = h0 + hh - 1, gw = w0 + ww - 1, gd = d - 1;
        float v = 0.f;
        if ((unsigned)gh < 56u && (unsigned)gw < 56u && (unsigned)gd < 56u)
            v = T1r[gh * HSTR + gw * 56 + gd];
        sIn[idx] = v;
    }
    __syncthreads();
    for (int idx = tid; idx < 5600; idx += 256) {
        int d = idx % 56; int t2 = idx / 56; int ww = t2 % 10; int hh = t2 / 10;
        const float* b = &sIn[(hh * 10 + ww) * 58 + d];
        sA[idx] = b[0] * kd0 + b[1] * kd1 + b[2] * kd2;
    }
    __syncthreads();
    const float k00 = kh0 * kw0, k01 = kh0 * kw1, k02 = kh0 * kw2;
    const float k10 = kh1 * kw0, k11 = kh1 * kw1, k12 = kh1 * kw2;
    const float k20 = kh2 * kw0, k21 = kh2 * kw1, k22 = kh2 * kw2;
    for (int idx = tid; idx < 3584; idx += 256) {
        int d = idx % 56; int t2 = idx / 56; int ww = t2 % 8; int hh = t2 / 8;
        const float* a = &sA[(hh * 10 + ww) * 56 + d];
        float acc = a[0]    * k00 + a[56]   * k01 + a[112]  * k02
                  + a[560]  * k10 + a[616]  * k11 + a[672]  * k12
                  + a[1120] * k20 + a[1176] * k21 + a[1232] * k22;
        T[(size_t)r * NP + (h0 + hh) * HSTR + (w0 + ww) * 56 + d] = acc;
    }
}

__global__ __launch_bounds__(256) void k3_out(
    float* T, const float* __restrict__ Ucout, const float* __restrict__ bias)
{
    __shared__ float sUo[RK * COUT];
    __shared__ float sB[COUT];
    const int tid = threadIdx.x;
    for (int t = tid; t < RK * COUT; t += 256) sUo[t] = Ucout[t];
    if (tid < COUT) sB[tid] = bias[tid];
    __syncthreads();
    const int p = blockIdx.x * 256 + tid;
    float acc[COUT];
#pragma unroll
    for (int o = 0; o < COUT; ++o) acc[o] = sB[o];
#pragma unroll 1
    for (int r = 0; r < RK; ++r) {
        float t = T[(size_t)r * NP + p];
        const float* Ur = &sUo[r * COUT];
#pragma unroll
        for (int o = 0; o < COUT; ++o) acc[o] += t * Ur[o];
    }
#pragma unroll
    for (int o = 0; o < COUT; ++o) T[(size_t)o * NP + p] = acc[o];
}

// ===================== launch =====================

extern "C" void kernel_launch(void* const* d_in, const int* in_sizes, int n_in,
                              void* d_out, int out_size, void* d_ws, size_t ws_size,
                              hipStream_t stream)
{
    const float* x     = (const float*)d_in[0];
    const float* Ukh   = (const float*)d_in[1];
    const float* Ukw   = (const float*)d_in[2];
    const float* Ukd   = (const float*)d_in[3];
    const float* Ucin  = (const float*)d_in[4];
    const float* Ucout = (const float*)d_in[5];
    const float* bias  = (const float*)d_in[6];

    const size_t t1_bytes = (size_t)RK * NP * sizeof(float);   // 37.2 MB

    if (ws_size >= t1_bytes + 8192) {
        float* T1 = (float*)d_ws;
        float* Ut = (float*)((char*)d_ws + t1_bytes);          // 6.8 KB
        k0_t<<<7, 256, 0, stream>>>(Ucin, Ut);
        k1d<<<HSTR / 4, 256, 0, stream>>>(x, Ut, Ukd, T1);     // 784 blocks
        k3c<<<NP2 / 64, 512, 0, stream>>>((const float2*)T1, Ucout, bias, Ukh,
                                          Ukw, (float2*)d_out);   // 1372 blocks
    } else {
        float* T = (float*)d_out;
        for (int r0 = 0; r0 < RK; r0 += 11) {
            int nr = (RK - r0 < 11) ? (RK - r0) : 11;
            k1_chunk<<<NP / 256, 256, 0, stream>>>(x, Ucin, T, r0, nr);
            k2_chunk<<<dim3(7, 7, nr), 256, 0, stream>>>(Ukh, Ukw, Ukd, T, r0);
        }
        k3_out<<<NP / 256, 256, 0, stream>>>(T, Ucout, bias);
    }
}

// Round 9
// 140.607 us; speedup vs baseline: 1.4797x; 1.0303x over previous
//
#include <hip/hip_runtime.h>

// CP-decomposed 3D conv (AirConv3D): B=1, Cin=32, Cout=64, 56^3, K=3, pad=1, rank=53.
// All-f32. History: R13 float4 two-phase k3 54us; R14 (512,4) VGPR-64 clamp ->
// spill catastrophe; R15 (512,2) no-spill but 16 waves/CU -> 84us; R16 k3c
// two-phase chunked float2 (LDS 13.8KB, VGPR<=64, 32 waves/CU) -> k3 < 49us,
// total 144.9. NEW FINDING (R16 profile): k1d = 50us, VGPR_Count=24 -> the
// compiler sank the predicated xv loads into the rank loop (xv[32] can't live
// in 24 regs): x re-read 53x from L1 at 30% occupancy (grid-limited, 3136
// waves) = latency-bound, both pipes idle.
// R17: k1d fixed: (a) clamped address + unconditional loads + asm keep-alive
// pins xv[32] in VGPRs (remat illegal); (b) grid (784,2) rank-split [0,27)/
// [27,53) -> 6272 waves (~77% slots). x re-read is L3-absorbed (FETCH 11MB
// < x 22.5MB already). Go/no-go: VGPR>=48, k1d 14-18us.
// NOTE: one ~44us fillBuffer (268MB ws re-poison) sits in the timed window.
// Pipeline: k0_t -> k1d -> k3c. Fallback (small ws): R5 pipeline (known good).

#define NP 175616   // 56*56*56
#define NP2 87808   // NP/2 float2 columns
#define HSTR 3136   // 56*56
#define H2 1568     // HSTR/2 float2 per h-plane
#define W2 28       // 56/2 float2 per w-row
#define CIN 32
#define RK 53
#define RC0 27      // rank chunk 0: [0,27)
#define COUT 64
#define SCR 53      // fallback scratch slice base in d_out

// ---- k0: Ut[r*32+c] = Ucin[c*53+r] ----
__global__ __launch_bounds__(256) void k0_t(const float* __restrict__ Ucin,
                                            float* __restrict__ Ut)
{
    int t = blockIdx.x * 256 + threadIdx.x;
    if (t < RK * CIN) {
        int r = t >> 5, c = t & 31;
        Ut[t] = Ucin[c * RK + r];
    }
}

// ---- k1d: T1d[r,p] = d-conv(sum_c x[c,p]*Ut[r][c]) via wave shfl ----
// Block = 256 threads = 4 waves; wave = one d-row (lanes 0..55 active).
// blockIdx.y picks rank half. xv pinned in VGPRs via asm keep-alive.
__global__ __launch_bounds__(256) void k1d(
    const float* __restrict__ x, const float* __restrict__ Ut,
    const float* __restrict__ Ukd, float* __restrict__ T1d)
{
    const int lane = threadIdx.x & 63;          // d index
    const int row  = blockIdx.x * 4 + (threadIdx.x >> 6);   // (h,w) row in [0,3136)
    const int p    = row * 56 + lane;
    const bool act = (lane < 56);
    const int pc   = act ? p : (p - 8);         // clamp: lanes 56..63 stay in-bounds

    float xv[CIN];
#pragma unroll
    for (int c = 0; c < CIN; ++c) xv[c] = x[c * NP + pc];
#pragma unroll
    for (int c = 0; c < CIN; ++c) asm volatile("" : "+v"(xv[c]));  // pin in VGPRs

    const int r0 = blockIdx.y ? RC0 : 0;
    const int r1 = blockIdx.y ? RK  : RC0;

#pragma unroll 2
    for (int r = r0; r < r1; ++r) {
        const float* U = Ut + r * CIN;          // uniform -> s_load
        float acc = 0.f;
#pragma unroll
        for (int c = 0; c < CIN; ++c) acc += xv[c] * U[c];
        // d-conv: out[d] = in[d-1]*kd0 + in[d]*kd1 + in[d+1]*kd2, zero pad
        float lm = __shfl_up(acc, 1, 64);
        float rp = __shfl_down(acc, 1, 64);
        if (lane == 0)  lm = 0.f;
        if (lane == 55) rp = 0.f;
        float res = lm * Ukd[r] + acc * Ukd[RK + r] + rp * Ukd[2 * RK + r];
        if (act) T1d[(size_t)r * NP + p] = res;
    }
}

// ---- k3c: two-phase chunked w+h conv + 53->64 projection + bias (R16) ----
__global__ __launch_bounds__(512, 4) void k3c(
    const float2* __restrict__ Ta, const float* __restrict__ Ucout,
    const float* __restrict__ bias, const float* __restrict__ Ukh,
    const float* __restrict__ Ukw, float2* __restrict__ Out)
{
    __shared__ float2 tld[RC0][64];              // 13824 B

    const int lane = threadIdx.x & 63;
    const int wv   = threadIdx.x >> 6;           // 0..7

    // bijective XCD swizzle (m204); nwg = 1372
    const int nwg = gridDim.x;
    const int qx = nwg >> 3, rx = nwg & 7;
    const int xcd = blockIdx.x & 7, loc = blockIdx.x >> 3;
    const int swz = ((xcd < rx) ? xcd * (qx + 1) : rx * (qx + 1) + (xcd - rx) * qx) + loc;

    const int q  = swz * 64 + lane;              // float2 column in [0,NP2)
    const int h  = q / H2;
    const int rm = q - h * H2;
    const int w  = rm / W2;
    const int om = (h > 0)  ? -H2 : 0;
    const int op = (h < 55) ?  H2 : 0;
    const int oa = (w > 0)  ? -W2 : 0;
    const int oc = (w < 55) ?  W2 : 0;
    const float mh0 = (h > 0)  ? 1.f : 0.f;
    const float mh2 = (h < 55) ? 1.f : 0.f;
    const float mw0 = (w > 0)  ? 1.f : 0.f;
    const float mw2 = (w < 55) ? 1.f : 0.f;

    const float2* Sq = Ta + q;
    const int og = __builtin_amdgcn_readfirstlane(wv << 3);  // 0,8,...,56

    float2 a[8];

    // ================= chunk 0: ranks [0,27) =================
#pragma unroll 1
    for (int r = wv; r < RC0; r += 8) {
        const float2* S = Sq + (size_t)r * NP2;
        const float kw0 = mw0 * Ukw[r];
        const float kw1 = Ukw[RK + r];
        const float kw2 = mw2 * Ukw[2 * RK + r];
        const float kh0 = mh0 * Ukh[r];
        const float kh1 = Ukh[RK + r];
        const float kh2 = mh2 * Ukh[2 * RK + r];
        float2 v00 = S[om + oa], v01 = S[om], v02 = S[om + oc];
        float2 v10 = S[oa],      v11 = S[0],  v12 = S[oc];
        float2 v20 = S[op + oa], v21 = S[op], v22 = S[op + oc];
        float2 t;
        t.x = (v00.x * kw0 + v01.x * kw1 + v02.x * kw2) * kh0
            + (v10.x * kw0 + v11.x * kw1 + v12.x * kw2) * kh1
            + (v20.x * kw0 + v21.x * kw1 + v22.x * kw2) * kh2;
        t.y = (v00.y * kw0 + v01.y * kw1 + v02.y * kw2) * kh0
            + (v10.y * kw0 + v11.y * kw1 + v12.y * kw2) * kh1
            + (v20.y * kw0 + v21.y * kw1 + v22.y * kw2) * kh2;
        tld[r][lane] = t;
    }
    __syncthreads();

#pragma unroll
    for (int o = 0; o < 8; ++o) {
        float b = bias[og + o];
        a[o].x = b; a[o].y = b;
    }
#pragma unroll 4
    for (int r = 0; r < RC0; ++r) {
        float2 t = tld[r][lane];
        const float* Ur = Ucout + r * COUT + og;         // uniform -> s_load
#pragma unroll
        for (int o = 0; o < 8; ++o) {
            float u = Ur[o];
            a[o].x += t.x * u; a[o].y += t.y * u;
        }
    }
    __syncthreads();                                     // protect LDS overwrite

    // ================= chunk 1: ranks [27,53) =================
#pragma unroll 1
    for (int r = RC0 + wv; r < RK; r += 8) {
        const float2* S = Sq + (size_t)r * NP2;
        const float kw0 = mw0 * Ukw[r];
        const float kw1 = Ukw[RK + r];
        const float kw2 = mw2 * Ukw[2 * RK + r];
        const float kh0 = mh0 * Ukh[r];
        const float kh1 = Ukh[RK + r];
        const float kh2 = mh2 * Ukh[2 * RK + r];
        float2 v00 = S[om + oa], v01 = S[om], v02 = S[om + oc];
        float2 v10 = S[oa],      v11 = S[0],  v12 = S[oc];
        float2 v20 = S[op + oa], v21 = S[op], v22 = S[op + oc];
        float2 t;
        t.x = (v00.x * kw0 + v01.x * kw1 + v02.x * kw2) * kh0
            + (v10.x * kw0 + v11.x * kw1 + v12.x * kw2) * kh1
            + (v20.x * kw0 + v21.x * kw1 + v22.x * kw2) * kh2;
        t.y = (v00.y * kw0 + v01.y * kw1 + v02.y * kw2) * kh0
            + (v10.y * kw0 + v11.y * kw1 + v12.y * kw2) * kh1
            + (v20.y * kw0 + v21.y * kw1 + v22.y * kw2) * kh2;
        tld[r - RC0][lane] = t;
    }
    __syncthreads();

#pragma unroll 4
    for (int r = RC0; r < RK; ++r) {
        float2 t = tld[r - RC0][lane];
        const float* Ur = Ucout + r * COUT + og;
#pragma unroll
        for (int o = 0; o < 8; ++o) {
            float u = Ur[o];
            a[o].x += t.x * u; a[o].y += t.y * u;
        }
    }

#pragma unroll
    for (int o = 0; o < 8; ++o)
        Out[(size_t)(og + o) * NP2 + q] = a[o];
}

// ===================== fallback path (R5, known good) =====================

__global__ __launch_bounds__(256) void k1_chunk(
    const float* __restrict__ x, const float* __restrict__ Ucin,
    float* T, int r0, int nr)
{
    __shared__ float sU[11 * CIN];
    const int tid = threadIdx.x;
    for (int t = tid; t < nr * CIN; t += 256) {
        int lr = t >> 5, c = t & 31;
        sU[t] = Ucin[c * RK + (r0 + lr)];
    }
    __syncthreads();
    const int p = blockIdx.x * 256 + tid;
    float xv[CIN];
#pragma unroll
    for (int c = 0; c < CIN; ++c) xv[c] = x[c * NP + p];
#pragma unroll 1
    for (int lr = 0; lr < nr; ++lr) {
        float acc = 0.f;
#pragma unroll
        for (int c = 0; c < CIN; ++c) acc += xv[c] * sU[lr * CIN + c];
        T[(size_t)(SCR + lr) * NP + p] = acc;
    }
}

__global__ __launch_bounds__(256) void k2_chunk(
    const float* __restrict__ Ukh, const float* __restrict__ Ukw,
    const float* __restrict__ Ukd, float* T, int r0)
{
    __shared__ float sIn[5800];
    __shared__ float sA[5600];
    const int lr = blockIdx.z;
    const int r  = r0 + lr;
    const int h0 = blockIdx.x * 8, w0 = blockIdx.y * 8;
    const int tid = threadIdx.x;
    const float kh0 = Ukh[r], kh1 = Ukh[RK + r], kh2 = Ukh[2 * RK + r];
    const float kw0 = Ukw[r], kw1 = Ukw[RK + r], kw2 = Ukw[2 * RK + r];
    const float kd0 = Ukd[r], kd1 = Ukd[RK + r], kd2 = Ukd[2 * RK + r];
    const float* T1r = T + (size_t)(SCR + lr) * NP;

    for (int idx = tid; idx < 5800; idx += 256) {
        int d = idx % 58; int t2 = idx / 58; int ww = t2 % 10; int hh = t2 / 10;
        int gh = h0 + hh - 1, gw = w0 + ww - 1, gd = d - 1;
        float v = 0.f;
        if ((unsigned)gh < 56u && (unsigned)gw < 56u && (unsigned)gd < 56u)
            v = T1r[gh * HSTR + gw * 56 + gd];
        sIn[idx] = v;
    }
    __syncthreads();
    for (int idx = tid; idx < 5600; idx += 256) {
        int d = idx % 56; int t2 = idx / 56; int ww = t2 % 10; int hh = t2 / 10;
        const float* b = &sIn[(hh * 10 + ww) * 58 + d];
        sA[idx] = b[0] * kd0 + b[1] * kd1 + b[2] * kd2;
    }
    __syncthreads();
    const float k00 = kh0 * kw0, k01 = kh0 * kw1, k02 = kh0 * kw2;
    const float k10 = kh1 * kw0, k11 = kh1 * kw1, k12 = kh1 * kw2;
    const float k20 = kh2 * kw0, k21 = kh2 * kw1, k22 = kh2 * kw2;
    for (int idx = tid; idx < 3584; idx += 256) {
        int d = idx % 56; int t2 = idx / 56; int ww = t2 % 8; int hh = t2 / 8;
        const float* a = &sA[(hh * 10 + ww) * 56 + d];
        float acc = a[0]    * k00 + a[56]   * k01 + a[112]  * k02
                  + a[560]  * k10 + a[616]  * k11 + a[672]  * k12
                  + a[1120] * k20 + a[1176] * k21 + a[1232] * k22;
        T[(size_t)r * NP + (h0 + hh) * HSTR + (w0 + ww) * 56 + d] = acc;
    }
}

__global__ __launch_bounds__(256) void k3_out(
    float* T, const float* __restrict__ Ucout, const float* __restrict__ bias)
{
    __shared__ float sUo[RK * COUT];
    __shared__ float sB[COUT];
    const int tid = threadIdx.x;
    for (int t = tid; t < RK * COUT; t += 256) sUo[t] = Ucout[t];
    if (tid < COUT) sB[tid] = bias[tid];
    __syncthreads();
    const int p = blockIdx.x * 256 + tid;
    float acc[COUT];
#pragma unroll
    for (int o = 0; o < COUT; ++o) acc[o] = sB[o];
#pragma unroll 1
    for (int r = 0; r < RK; ++r) {
        float t = T[(size_t)r * NP + p];
        const float* Ur = &sUo[r * COUT];
#pragma unroll
        for (int o = 0; o < COUT; ++o) acc[o] += t * Ur[o];
    }
#pragma unroll
    for (int o = 0; o < COUT; ++o) T[(size_t)o * NP + p] = acc[o];
}

// ===================== launch =====================

extern "C" void kernel_launch(void* const* d_in, const int* in_sizes, int n_in,
                              void* d_out, int out_size, void* d_ws, size_t ws_size,
                              hipStream_t stream)
{
    const float* x     = (const float*)d_in[0];
    const float* Ukh   = (const float*)d_in[1];
    const float* Ukw   = (const float*)d_in[2];
    const float* Ukd   = (const float*)d_in[3];
    const float* Ucin  = (const float*)d_in[4];
    const float* Ucout = (const float*)d_in[5];
    const float* bias  = (const float*)d_in[6];

    const size_t t1_bytes = (size_t)RK * NP * sizeof(float);   // 37.2 MB

    if (ws_size >= t1_bytes + 8192) {
        float* T1 = (float*)d_ws;
        float* Ut = (float*)((char*)d_ws + t1_bytes);          // 6.8 KB
        k0_t<<<7, 256, 0, stream>>>(Ucin, Ut);
        k1d<<<dim3(HSTR / 4, 2), 256, 0, stream>>>(x, Ut, Ukd, T1);  // 1568 blocks
        k3c<<<NP2 / 64, 512, 0, stream>>>((const float2*)T1, Ucout, bias, Ukh,
                                          Ukw, (float2*)d_out);      // 1372 blocks
    } else {
        float* T = (float*)d_out;
        for (int r0 = 0; r0 < RK; r0 += 11) {
            int nr = (RK - r0 < 11) ? (RK - r0) : 11;
            k1_chunk<<<NP / 256, 256, 0, stream>>>(x, Ucin, T, r0, nr);
            k2_chunk<<<dim3(7, 7, nr), 256, 0, stream>>>(Ukh, Ukw, Ukd, T, r0);
        }
        k3_out<<<NP / 256, 256, 0, stream>>>(T, Ucout, bias);
    }
}